// Round 5
// baseline (283.817 us; speedup 1.0000x reference)
//
#include <hip/hip_runtime.h>

// AttributeDecoder R5: algorithm inversion.
// Instead of gathering K*S=393216 random 1KB rows (402 MB @ ~2.5 TB/s = 80 us
// floor, measured R2/R4), compute logits for ALL 131072 rows as a dense
// streaming GEMM (128 MB sequential read + 50 MB bf16 write) then gather
// 32 B/selection from the L3-resident logits table.
// Phase 1: C(131072x192) = feats @ W_all + bias, bf16 MFMA, B-frags in
//   registers (wave covers 48 cols), A-frags packed straight from global
//   (16 consecutive rows, lines fully consumed).
// Phase 2: out[k,s,:] = logits[mask_idx[k,s]][k*8..+7], 8B loads, f32 stores.
// Fallback to the R2 wave-per-s kernel if ws_size < 50.4 MB.

#define KH 24
#define SS 16384
#define VV 8
#define DD 256
#define NG 192          // 24 heads * 8 logits
#define NROWS 131072

typedef short bf16x8 __attribute__((ext_vector_type(8)));
typedef float f32x4  __attribute__((ext_vector_type(4)));
typedef int   i32x4  __attribute__((ext_vector_type(4)));

__device__ __forceinline__ unsigned short f32_bf16_rne(float f) {
    unsigned u = __builtin_bit_cast(unsigned, f);
    u = (u + 0x7FFFu + ((u >> 16) & 1u)) >> 16;
    return (unsigned short)u;
}

__device__ __forceinline__ unsigned pack_bf16x2(float lo, float hi) {
    unsigned ulo = __builtin_bit_cast(unsigned, lo) + 0x8000u;
    unsigned uhi = __builtin_bit_cast(unsigned, hi) + 0x8000u;
    return __builtin_amdgcn_perm(uhi, ulo, 0x07060302);  // [hi.b3,hi.b2,lo.b3,lo.b2]
}

// ---------------- Phase 1: dense logits ----------------
__global__ __launch_bounds__(256, 3) void dense_logits_kernel(
    const float* __restrict__ feats,        // (131072, 256)
    const float* __restrict__ head_w,       // (24, 256, 8)
    const float* __restrict__ head_b,       // (24, 8)
    unsigned short* __restrict__ logits)    // (131072, 192) bf16
{
    const int lane = threadIdx.x & 63;
    const int wv   = threadIdx.x >> 6;      // wave covers cols wv*48..+47
    const int n    = lane & 15;
    const int q    = lane >> 4;

    // Register B-frags: Bf[tile][t][j] = W_all[t*32+q*8+j][wv*48+tile*16+n]
    // where W_all[kd][k*8+v] = head_w[k][kd][v]. One-time scattered setup,
    // amortized over 16 m-tiles.
    bf16x8 Bf[3][8];
    float  bias_v[3];
#pragma unroll
    for (int tile = 0; tile < 3; ++tile) {
        const int n_g = wv * 48 + tile * 16 + n;
        const float* Wh = head_w + (size_t)(n_g >> 3) * (DD * VV) + (n_g & 7);
#pragma unroll
        for (int t = 0; t < 8; ++t)
#pragma unroll
            for (int j = 0; j < 8; ++j)
                Bf[tile][t][j] = (short)f32_bf16_rne(Wh[(t * 32 + q * 8 + j) * VV]);
        bias_v[tile] = head_b[(n_g >> 3) * VV + (n_g & 7)];
    }

    const int rbase = blockIdx.x * 256;     // 256 rows per block, 16 m-tiles
#pragma unroll 1
    for (int mt = 0; mt < 16; ++mt) {
        const int mbase = rbase + mt * 16;
        const float* p = feats + (size_t)(mbase + n) * DD + q * 8;

        f32x4 acc[3];
#pragma unroll
        for (int tile = 0; tile < 3; ++tile) {
            const float b = bias_v[tile];   // bias baked into accumulator
            acc[tile][0] = b; acc[tile][1] = b; acc[tile][2] = b; acc[tile][3] = b;
        }
#pragma unroll
        for (int t = 0; t < 8; ++t) {
            const float4 a0 = *(const float4*)(p + t * 32);
            const float4 a1 = *(const float4*)(p + t * 32 + 4);
            i32x4 ai;
            ai[0] = (int)pack_bf16x2(a0.x, a0.y);
            ai[1] = (int)pack_bf16x2(a0.z, a0.w);
            ai[2] = (int)pack_bf16x2(a1.x, a1.y);
            ai[3] = (int)pack_bf16x2(a1.z, a1.w);
            const bf16x8 a = __builtin_bit_cast(bf16x8, ai);
            acc[0] = __builtin_amdgcn_mfma_f32_16x16x32_bf16(a, Bf[0][t], acc[0], 0, 0, 0);
            acc[1] = __builtin_amdgcn_mfma_f32_16x16x32_bf16(a, Bf[1][t], acc[1], 0, 0, 0);
            acc[2] = __builtin_amdgcn_mfma_f32_16x16x32_bf16(a, Bf[2][t], acc[2], 0, 0, 0);
        }
        // C[m = q*4+i][n_g], row pitch 192 shorts
#pragma unroll
        for (int tile = 0; tile < 3; ++tile) {
            const int n_g = wv * 48 + tile * 16 + n;
            unsigned short* op = logits + (size_t)(mbase + q * 4) * NG + n_g;
#pragma unroll
            for (int i = 0; i < 4; ++i)
                op[(size_t)i * NG] = f32_bf16_rne(acc[tile][i]);
        }
    }
}

// ---------------- Phase 2: 32B-slice gather ----------------
__global__ __launch_bounds__(256) void gather_logits_kernel(
    const unsigned short* __restrict__ logits,  // (131072, 192) bf16
    const int* __restrict__ mask_idx,           // (24, 16384)
    float* __restrict__ out)                    // (24, 16384, 8)
{
    const int tid  = blockIdx.x * 256 + threadIdx.x;
    const int gsel = tid >> 1;                  // 2 lanes per selection
    const int half = tid & 1;
    const int k    = gsel >> 14;                // S = 16384
    const int idx  = mask_idx[gsel];
    const unsigned short* lp = logits + (size_t)idx * NG + k * VV + half * 4;
    const ushort4 u = *(const ushort4*)lp;      // 8B load
    float4 r;
    r.x = __builtin_bit_cast(float, (unsigned)u.x << 16);
    r.y = __builtin_bit_cast(float, (unsigned)u.y << 16);
    r.z = __builtin_bit_cast(float, (unsigned)u.z << 16);
    r.w = __builtin_bit_cast(float, (unsigned)u.w << 16);
    *(float4*)(out + (size_t)gsel * VV + half * 4) = r;   // coalesced 1KB/wave
}

// ---------------- Fallback (R2, 82.5 us) if ws too small ----------------
template <int CTRL>
__device__ __forceinline__ float dpp_mov(float x) {
    int xi = __builtin_bit_cast(int, x);
    int r = __builtin_amdgcn_update_dpp(xi, xi, CTRL, 0xF, 0xF, false);
    return __builtin_bit_cast(float, r);
}

__device__ __forceinline__ float reduce8(const float acc[8], int lane) {
    const bool b0 = lane & 1;
    const bool b1 = lane & 2;
    const bool b2 = lane & 4;
    float a4[4];
#pragma unroll
    for (int j = 0; j < 4; ++j) {
        const float keep = b0 ? acc[2 * j + 1] : acc[2 * j];
        const float send = b0 ? acc[2 * j] : acc[2 * j + 1];
        a4[j] = keep + dpp_mov<0xB1>(send);
    }
    float a2[2];
#pragma unroll
    for (int m = 0; m < 2; ++m) {
        const float keep = b1 ? a4[2 * m + 1] : a4[2 * m];
        const float send = b1 ? a4[2 * m] : a4[2 * m + 1];
        a2[m] = keep + dpp_mov<0x4E>(send);
    }
    const float keep = b2 ? a2[1] : a2[0];
    const float send = b2 ? a2[0] : a2[1];
    float a1 = keep + __shfl_xor(send, 4, 64);
    a1 += dpp_mov<0x128>(a1);
    a1 += __shfl_xor(a1, 16, 64);
    a1 += __shfl_xor(a1, 32, 64);
    return a1;
}

__global__ __launch_bounds__(256) void attr_decoder_fallback(
    const float* __restrict__ feats, const int* __restrict__ mask_idx,
    const float* __restrict__ head_w, const float* __restrict__ head_b,
    float* __restrict__ out)
{
    const int lane  = threadIdx.x & 63;
    const int wvv   = threadIdx.x >> 6;
    const int k     = blockIdx.x >> 7;
    const int chunk = blockIdx.x & 127;
    const float* Wk = head_w + (size_t)k * (DD * VV);
    float w[4][8];
#pragma unroll
    for (int t = 0; t < 4; ++t) {
        const float4 a = *(const float4*)(Wk + (lane * 4 + t) * VV);
        const float4 b = *(const float4*)(Wk + (lane * 4 + t) * VV + 4);
        w[t][0] = a.x; w[t][1] = a.y; w[t][2] = a.z; w[t][3] = a.w;
        w[t][4] = b.x; w[t][5] = b.y; w[t][6] = b.z; w[t][7] = b.w;
    }
    const float bias = head_b[k * VV + (lane & 7)];
    const float4* feats4 = (const float4*)feats;
    const int s_base = chunk * 128 + wvv * 32;
    const int* mi = mask_idx + k * SS + s_base;
    float* outp = out + ((size_t)k * SS + s_base) * VV;
    const int g = (lane >> 3) & 3;
    for (int i = 0; i < 32; i += 4) {
        const int4 rows = *(const int4*)(mi + i);
        const float4 f0 = feats4[(size_t)rows.x * 64 + lane];
        const float4 f1 = feats4[(size_t)rows.y * 64 + lane];
        const float4 f2 = feats4[(size_t)rows.z * 64 + lane];
        const float4 f3 = feats4[(size_t)rows.w * 64 + lane];
        float r[4];
        const float4 f[4] = {f0, f1, f2, f3};
#pragma unroll
        for (int u = 0; u < 4; ++u) {
            float acc[8];
#pragma unroll
            for (int v = 0; v < 8; ++v) {
                acc[v] = f[u].x * w[0][v];
                acc[v] = fmaf(f[u].y, w[1][v], acc[v]);
                acc[v] = fmaf(f[u].z, w[2][v], acc[v]);
                acc[v] = fmaf(f[u].w, w[3][v], acc[v]);
            }
            r[u] = reduce8(acc, lane);
        }
        const float r01 = (g & 1) ? r[1] : r[0];
        const float r23 = (g & 1) ? r[3] : r[2];
        const float val = ((g & 2) ? r23 : r01) + bias;
        if (lane < 32) outp[i * VV + lane] = val;
    }
}

extern "C" void kernel_launch(void* const* d_in, const int* in_sizes, int n_in,
                              void* d_out, int out_size, void* d_ws, size_t ws_size,
                              hipStream_t stream) {
    // d_in[0] = block_type_grid (unused by reference)
    const float* feats    = (const float*)d_in[1];
    const int*   mask_idx = (const int*)  d_in[2];
    const float* head_w   = (const float*)d_in[3];
    const float* head_b   = (const float*)d_in[4];
    float* out = (float*)d_out;

    const size_t need = (size_t)NROWS * NG * sizeof(unsigned short);  // 50.3 MB
    if (ws_size >= need) {
        unsigned short* logits = (unsigned short*)d_ws;
        dense_logits_kernel<<<dim3(NROWS / 256), dim3(256), 0, stream>>>(
            feats, head_w, head_b, logits);
        gather_logits_kernel<<<dim3(KH * SS * 2 / 256), dim3(256), 0, stream>>>(
            logits, mask_idx, out);
    } else {
        attr_decoder_fallback<<<dim3(KH * 128), dim3(256), 0, stream>>>(
            feats, mask_idx, head_w, head_b, out);
    }
}